// Round 7
// baseline (6388.974 us; speedup 1.0000x reference)
//
#include <hip/hip_runtime.h>
#include <hip/hip_bf16.h>
#include <cmath>

#define T_LEN 4096
#define BATCH 16
typedef __hip_bfloat16 bf16;
typedef unsigned short u16;
typedef float f32x4 __attribute__((ext_vector_type(4)));
typedef short s16x8 __attribute__((ext_vector_type(8)));
typedef unsigned short u16x8 __attribute__((ext_vector_type(8)));

__device__ __forceinline__ float ldx(const void* p, int dt, size_t i) {
    return dt ? __bfloat162float(((const bf16*)p)[i]) : ((const float*)p)[i];
}
__device__ __forceinline__ void stx(void* p, int dt, size_t i, float v) {
    if (dt) ((bf16*)p)[i] = __float2bfloat16(v);
    else ((float*)p)[i] = v;
}
__device__ __forceinline__ u16 f2b(float v) {
    bf16 h = __float2bfloat16(v);
    return *(u16*)&h;
}
__device__ __forceinline__ float b2f(u16 u) {
    return __bfloat162float(*(const bf16*)&u);
}

// ---------------------------------------------------------------- dtype probe
__global__ void detect_kernel(const float* __restrict__ x, int* __restrict__ flag) {
    __shared__ int s[256];
    int tid = threadIdx.x;
    int bad = 0;
    for (int i = tid; i < 2048; i += 256) {
        float v = x[i];
        if (!(fabsf(v) < 1e30f)) bad = 1;
    }
    s[tid] = bad;
    __syncthreads();
    for (int off = 128; off > 0; off >>= 1) {
        if (tid < off) s[tid] |= s[tid + off];
        __syncthreads();
    }
    if (tid == 0) *flag = s[0];
}

// ---------------------------------------------------------------- spk norm
__global__ void spk_norm_kernel(const int* __restrict__ dflag,
                                const void* __restrict__ spk,
                                float* __restrict__ out) {
    const int f = *dflag;
    int s = blockIdx.x, d = threadIdx.x;
    float v = ldx(spk, f, (size_t)s * 128 + d);
    __shared__ float red[128];
    red[d] = v * v;
    __syncthreads();
    for (int off = 64; off > 0; off >>= 1) {
        if (d < off) red[d] += red[d + off];
        __syncthreads();
    }
    float rs = rsqrtf(red[0]);
    out[s * 128 + d] = v * rs;
}

// ---------------------------------------------------------------- weight repack
// dst: [K][ocp][Cinp] bf16, zero-padded. wmode0: src [Cout][Cin][K].
__global__ __launch_bounds__(256) void repack0_kernel(
    const int* __restrict__ dflag, const void* __restrict__ src,
    int Cout, int Cin, int K, int ocp, int Cinp,
    bf16* __restrict__ dsthi, bf16* __restrict__ dstlo) {
    const int F = *dflag;
    __shared__ u16 sh[64 * 32 * 5];
    __shared__ u16 sl[64 * 32 * 5];
    const int ic0 = blockIdx.x * 32;
    const int oc0 = blockIdx.y * 64;
    const int tid = threadIdx.x;
    const int N = 64 * 32 * K;
    for (int idx = tid; idx < N; idx += 256) {
        int ocl = idx / (32 * K);
        int r = idx % (32 * K);
        int icl = r / K, k = r % K;
        int oc = oc0 + ocl, ic = ic0 + icl;
        float v = 0.f;
        if (oc < Cout && ic < Cin)
            v = ldx(src, F, ((size_t)oc * Cin + ic) * K + k);
        u16 hb = f2b(v);
        sh[(ocl * 32 + icl) * K + k] = hb;
        sl[(ocl * 32 + icl) * K + k] = f2b(v - b2f(hb));
    }
    __syncthreads();
    const int M = K * 64 * 4;  // units of 8 ic
    for (int idx = tid; idx < M; idx += 256) {
        int k = idx / (64 * 4);
        int r = idx % (64 * 4);
        int ocl = r >> 2;
        int g8 = (r & 3) << 3;
        u16x8 h, l;
#pragma unroll
        for (int j = 0; j < 8; j++) {
            h[j] = sh[(ocl * 32 + g8 + j) * K + k];
            l[j] = sl[(ocl * 32 + g8 + j) * K + k];
        }
        size_t off = ((size_t)k * ocp + oc0 + ocl) * Cinp + ic0 + g8;
        *(u16x8*)&dsthi[off] = h;
        if (dstlo) *(u16x8*)&dstlo[off] = l;
    }
}

// wmode1 (convT): src [Cin][Cout][K]; W_eff[o][i][k]=src[i][o][K-1-k].
__global__ __launch_bounds__(256) void repack1_kernel(
    const int* __restrict__ dflag, const void* __restrict__ src,
    int Cout, int Cin, int K, int ocp, int Cinp,
    bf16* __restrict__ dsthi) {
    const int F = *dflag;
    __shared__ u16 sh[64 * 32 * 5];
    const int ic0 = blockIdx.x * 64;
    const int oc0 = blockIdx.y * 32;
    const int tid = threadIdx.x;
    const int N = 64 * 32 * K;
    for (int idx = tid; idx < N; idx += 256) {
        int icl = idx / (32 * K);
        int r = idx % (32 * K);
        int ocl = r / K, k = r % K;
        int oc = oc0 + ocl, ic = ic0 + icl;
        float v = 0.f;
        if (oc < Cout && ic < Cin)
            v = ldx(src, F, ((size_t)ic * Cout + oc) * K + k);
        sh[(icl * 32 + ocl) * K + (K - 1 - k)] = f2b(v);
    }
    __syncthreads();
    const int M = K * 32 * 8;
    for (int idx = tid; idx < M; idx += 256) {
        int k = idx / (32 * 8);
        int r = idx % (32 * 8);
        int ocl = r >> 3;
        int g8 = (r & 7) << 3;
        u16x8 h;
#pragma unroll
        for (int j = 0; j < 8; j++)
            h[j] = sh[((g8 + j) * 32 + ocl) * K + k];
        size_t off = ((size_t)k * ocp + oc0 + ocl) * Cinp + ic0 + g8;
        *(u16x8*)&dsthi[off] = h;
    }
}

// ---------------------------------------------------------------- x prep
__global__ void xprep_kernel(const int* __restrict__ dflag,
                             const void* __restrict__ x, int b0,
                             bf16* __restrict__ xp) {
    const int F = *dflag;
    int b = blockIdx.y;
    int t = blockIdx.x * 256 + threadIdx.x;
    size_t src = ((size_t)(b0 + b) * T_LEN + t) * 80;
    u16* row = (u16*)xp + ((size_t)b * T_LEN + t) * 192;
    for (int c4 = 0; c4 < 96; c4 += 4) {
        ushort4 h, l;
        u16* hp = (u16*)&h;
        u16* lp = (u16*)&l;
        for (int j = 0; j < 4; j++) {
            int c = c4 + j;
            float v = (c < 80) ? ldx(x, F, src + c) : 0.f;
            u16 hb = f2b(v);
            hp[j] = hb;
            lp[j] = f2b(v - b2f(hb));
        }
        *(ushort4*)&row[c4] = h;
        *(ushort4*)&row[96 + c4] = l;
    }
}

// ---------------------------------------------------------------- ye scatter
__global__ void ye_kernel(const int* __restrict__ y, int b0,
                          const float* __restrict__ spk_n,
                          bf16* __restrict__ D1, bf16* __restrict__ D2,
                          bf16* __restrict__ D3) {
    int b = blockIdx.y;
    int t = blockIdx.x * 256 + threadIdx.x;
    int idx = y[(size_t)(b0 + b) * T_LEN + t];
    const float* s = spk_n + (size_t)idx * 128;
    size_t r = (size_t)b * T_LEN + t;
    u16* p1 = (u16*)D1 + r * 192 + 64;
    u16* p2 = (u16*)D2 + r * 640 + 512;
    u16* p3 = (u16*)D3 + r * 640 + 512;
    for (int d4 = 0; d4 < 128; d4 += 4) {
        float4 v = *(const float4*)&s[d4];
        ushort4 h;
        h.x = f2b(v.x); h.y = f2b(v.y); h.z = f2b(v.z); h.w = f2b(v.w);
        *(ushort4*)&p1[d4] = h;
        *(ushort4*)&p2[d4] = h;
        *(ushort4*)&p3[d4] = h;
    }
}

// ---------------------------------------------------------------- MFMA conv
// Implicit GEMM, BARRIER-FREE: block = 256t x 64oc, 4 waves each owning a
// disjoint 64t slice with a PRIVATE LDS staging region (producer == consumer
// => no __syncthreads; only in-wave s_waitcnt lgkmcnt). B (weights) read
// directly from global (L1/L2; all 4 waves share the same 64-oc slice).
// A: bf16 rows [b][t][RS], hi at col 0, lo at col loOff (PLANES==2).
// W: repacked [K][ocp][Cinp]. aloMode: 0 never, 1 always, 2 iff flag==0.
// wloMode: 2 => extra W-lo pass iff flag==0.
template <int KK, int PLANES>
__global__ __launch_bounds__(256, 4) void conv_mfma(
    const int* __restrict__ dflag,
    const bf16* __restrict__ act, int RS, int loOff, int aloMode, int Cinp,
    const bf16* __restrict__ whi, const bf16* __restrict__ wlo, int wloMode,
    int ocp, const void* __restrict__ bias,
    void* __restrict__ outp, int odt, int oRS, int ocMax, int boff) {
    constexpr int PAD = (KK - 1) / 2;
    constexpr int WROWS = 64 + KK - 1;       // wave-private halo rows
    constexpr int WSTR = 40;                 // padded cols (32 + 8)
    const int F = *dflag;
    const bool useALo = (PLANES == 2) && ((aloMode == 1) || (aloMode == 2 && F == 0));
    const bool useWLo = (wloMode == 2 && F == 0) && (wlo != nullptr);
    const int oc0 = blockIdx.y * 64;
    const int b = blockIdx.z;
    const int tid = threadIdx.x;
    const int lane = tid & 63;
    const int wid = tid >> 6;
    const int t0w = blockIdx.x * 256 + wid * 64;   // wave's t base
    const int l16 = lane & 15;
    const int quad = lane >> 4;
    const int q8 = quad * 8;

    __shared__ __align__(16) bf16 sAll[4 * PLANES * WROWS * WSTR];
    bf16* sW = &sAll[wid * (PLANES * WROWS * WSTR)];   // this wave's region
    bf16* sWlo = sW + WROWS * WSTR;

    const u16* wrow_hi = (const u16*)whi + (size_t)(oc0 + l16) * Cinp + q8;
    const u16* wrow_lo = useWLo
        ? (const u16*)wlo + (size_t)(oc0 + l16) * Cinp + q8 : nullptr;

    f32x4 acc[4][4];
#pragma unroll
    for (int i = 0; i < 4; i++)
#pragma unroll
        for (int j = 0; j < 4; j++) acc[i][j] = (f32x4){0.f, 0.f, 0.f, 0.f};

    const int nch = Cinp >> 5;
    for (int ch = 0; ch < nch; ch++) {
        const int ic0 = ch << 5;
        // WAR guard: all prior ds_reads of this region retired before overwrite
        asm volatile("s_waitcnt lgkmcnt(0)" ::: "memory");
        // ---- wave-private staging: WROWS rows x 32 ic (16B units)
        for (int g = lane; g < WROWS * 4; g += 64) {
            int row = g >> 2, c8 = (g & 3) << 3;
            int t = t0w - PAD + row;
            u16x8 v = (u16x8){0, 0, 0, 0, 0, 0, 0, 0};
            u16x8 vl = (u16x8){0, 0, 0, 0, 0, 0, 0, 0};
            if (t >= 0 && t < T_LEN) {
                const u16* src = (const u16*)act + ((size_t)b * T_LEN + t) * RS + ic0 + c8;
                v = *(const u16x8*)src;
                if (useALo) vl = *(const u16x8*)(src + loOff);
            }
            *(u16x8*)&sW[row * WSTR + c8] = v;
            if (useALo) *(u16x8*)&sWlo[row * WSTR + c8] = vl;
        }
        // RAW guard: staging writes visible before reads (same wave, in-order pipe)
        asm volatile("s_waitcnt lgkmcnt(0)" ::: "memory");

#pragma unroll
        for (int tap = 0; tap < KK; tap++) {
            s16x8 bfr[4];
#pragma unroll
            for (int ni = 0; ni < 4; ni++)
                bfr[ni] = *(const s16x8*)(wrow_hi +
                    ((size_t)tap * ocp + ni * 16) * Cinp + ic0);
#pragma unroll
            for (int mi = 0; mi < 4; mi++) {
                int row = mi * 16 + l16 + tap;
                s16x8 a = *(const s16x8*)&sW[row * WSTR + q8];
#pragma unroll
                for (int ni = 0; ni < 4; ni++)
                    acc[mi][ni] = __builtin_amdgcn_mfma_f32_16x16x32_bf16(
                        a, bfr[ni], acc[mi][ni], 0, 0, 0);
                if (useALo) {
                    s16x8 al = *(const s16x8*)&sWlo[row * WSTR + q8];
#pragma unroll
                    for (int ni = 0; ni < 4; ni++)
                        acc[mi][ni] = __builtin_amdgcn_mfma_f32_16x16x32_bf16(
                            al, bfr[ni], acc[mi][ni], 0, 0, 0);
                }
            }
        }
        if (useWLo) {
#pragma unroll
            for (int tap = 0; tap < KK; tap++) {
                s16x8 bfr[4];
#pragma unroll
                for (int ni = 0; ni < 4; ni++)
                    bfr[ni] = *(const s16x8*)(wrow_lo +
                        ((size_t)tap * ocp + ni * 16) * Cinp + ic0);
#pragma unroll
                for (int mi = 0; mi < 4; mi++) {
                    int row = mi * 16 + l16 + tap;
                    s16x8 a = *(const s16x8*)&sW[row * WSTR + q8];
#pragma unroll
                    for (int ni = 0; ni < 4; ni++)
                        acc[mi][ni] = __builtin_amdgcn_mfma_f32_16x16x32_bf16(
                            a, bfr[ni], acc[mi][ni], 0, 0, 0);
                }
            }
        }
    }

    // ---- epilogue: D row = quad*4+r (t), col = l16 (oc)
#pragma unroll
    for (int ni = 0; ni < 4; ni++) {
        int oc = oc0 + ni * 16 + l16;
        if (oc >= ocMax) continue;
        float bv = ldx(bias, F, oc);
#pragma unroll
        for (int mi = 0; mi < 4; mi++) {
#pragma unroll
            for (int r = 0; r < 4; r++) {
                int t = t0w + mi * 16 + quad * 4 + r;
                float v = acc[mi][ni][r] + bv;
                size_t off = ((size_t)(b + boff) * T_LEN + t) * (size_t)oRS + oc;
                if (odt == 0) ((float*)outp)[off] = v;
                else if (odt == 1) ((bf16*)outp)[off] = __float2bfloat16(v);
                else stx(outp, F, off, v);
            }
        }
    }
}

// ---------------------------------------------------------------- LN + LeakyReLU
__global__ __launch_bounds__(256) void ln_lrelu(
    const int* __restrict__ dflag, const float* __restrict__ Fin,
    bf16* __restrict__ E, const void* __restrict__ g, const void* __restrict__ bt) {
    const int Fl = *dflag;
    int b = blockIdx.y;
    int t = blockIdx.x * 4 + (threadIdx.x >> 6);
    int lane = threadIdx.x & 63;
    const float* row = Fin + ((size_t)b * T_LEN + t) * 512 + lane * 8;
    float vv[8];
    *(float4*)&vv[0] = *(const float4*)row;
    *(float4*)&vv[4] = *(const float4*)(row + 4);
    float s = 0.f, s2 = 0.f;
#pragma unroll
    for (int j = 0; j < 8; j++) { s += vv[j]; s2 += vv[j] * vv[j]; }
    for (int m = 32; m; m >>= 1) {
        s += __shfl_xor(s, m);
        s2 += __shfl_xor(s2, m);
    }
    float mean = s / 512.f;
    float var = s2 / 512.f - mean * mean;
    float rstd = rsqrtf(var + 1e-5f);
    u16* eo = (u16*)E + ((size_t)b * T_LEN + t) * 1024 + lane * 8;
    ushort4 h[2], l[2];
#pragma unroll
    for (int j = 0; j < 8; j++) {
        int c = lane * 8 + j;
        float v = (vv[j] - mean) * rstd * ldx(g, Fl, c) + ldx(bt, Fl, c);
        v = v >= 0.f ? v : 0.2f * v;
        u16 hb = f2b(v);
        ((u16*)h)[j] = hb;
        ((u16*)l)[j] = f2b(v - b2f(hb));
    }
    *(ushort4*)&eo[0] = h[0];
    *(ushort4*)&eo[4] = h[1];
    *(ushort4*)&eo[512] = l[0];
    *(ushort4*)&eo[516] = l[1];
}

// ---------------------------------------------------------------- LN + GLU
__global__ __launch_bounds__(256) void ln_glu(
    const int* __restrict__ dflag, const bf16* __restrict__ Fin,
    bf16* __restrict__ D, int oRS, const void* __restrict__ g,
    const void* __restrict__ bt) {
    const int Fl = *dflag;
    int b = blockIdx.y;
    int t = blockIdx.x * 4 + (threadIdx.x >> 6);
    int lane = threadIdx.x & 63;
    const u16* row = (const u16*)Fin + ((size_t)b * T_LEN + t) * 1024;
    ushort4 ua[2], ug[2];
    ua[0] = *(const ushort4*)&row[lane * 8];
    ua[1] = *(const ushort4*)&row[lane * 8 + 4];
    ug[0] = *(const ushort4*)&row[512 + lane * 8];
    ug[1] = *(const ushort4*)&row[512 + lane * 8 + 4];
    float av[8], gv[8];
#pragma unroll
    for (int j = 0; j < 8; j++) {
        av[j] = b2f(((u16*)ua)[j]);
        gv[j] = b2f(((u16*)ug)[j]);
    }
    float s = 0.f, s2 = 0.f;
#pragma unroll
    for (int j = 0; j < 8; j++) {
        s += av[j] + gv[j];
        s2 += av[j] * av[j] + gv[j] * gv[j];
    }
    for (int m = 32; m; m >>= 1) {
        s += __shfl_xor(s, m);
        s2 += __shfl_xor(s2, m);
    }
    float mean = s / 1024.f;
    float var = s2 / 1024.f - mean * mean;
    float rstd = rsqrtf(var + 1e-5f);
    ushort4 o[2];
#pragma unroll
    for (int j = 0; j < 8; j++) {
        int c = lane * 8 + j;
        float a = (av[j] - mean) * rstd * ldx(g, Fl, c) + ldx(bt, Fl, c);
        float gg = (gv[j] - mean) * rstd * ldx(g, Fl, 512 + c) + ldx(bt, Fl, 512 + c);
        ((u16*)o)[j] = f2b(a / (1.f + expf(-gg)));
    }
    u16* op = (u16*)D + ((size_t)b * T_LEN + t) * oRS + lane * 8;
    *(ushort4*)&op[0] = o[0];
    *(ushort4*)&op[4] = o[1];
}

// ---------------------------------------------------------------- VQ
__global__ __launch_bounds__(256) void vq_kernel(
    const int* __restrict__ dflag, const float* __restrict__ z,
    const void* __restrict__ cb, bf16* __restrict__ D1) {
    const int F = *dflag;
    int b = blockIdx.y;
    int t = blockIdx.x * 256 + threadIdx.x;
    int tid = threadIdx.x;

    __shared__ float sCB[128 * 64];
    __shared__ float sCC[128];

    float zr[64];
    const float* zp = z + ((size_t)b * T_LEN + t) * 64;
#pragma unroll
    for (int d4 = 0; d4 < 64; d4 += 4) *(float4*)&zr[d4] = *(const float4*)&zp[d4];
    float zz = 0.f;
#pragma unroll
    for (int d = 0; d < 64; d++) zz += zr[d] * zr[d];

    float best = 3.4e38f;
    int bidx = 0;
    for (int chunk = 0; chunk < 4; chunk++) {
        __syncthreads();
        for (int i = tid; i < 8192; i += 256)
            sCB[i] = ldx(cb, F, (size_t)chunk * 8192 + i);
        __syncthreads();
        if (tid < 128) {
            float cc = 0.f;
#pragma unroll 8
            for (int d = 0; d < 64; d++) {
                float cv = sCB[tid * 64 + d];
                cc += cv * cv;
            }
            sCC[tid] = cc;
        }
        __syncthreads();
        for (int c = 0; c < 128; c++) {
            const float* cp = &sCB[c * 64];
            float dot = 0.f;
#pragma unroll
            for (int d = 0; d < 64; d++) dot += zr[d] * cp[d];
            float dist = zz + sCC[c] - 2.f * dot;
            if (dist < best) { best = dist; bidx = chunk * 128 + c; }
        }
    }
    u16* out = (u16*)D1 + ((size_t)b * T_LEN + t) * 192;
    for (int d4 = 0; d4 < 64; d4 += 4) {
        ushort4 h;
        h.x = f2b(ldx(cb, F, (size_t)bidx * 64 + d4));
        h.y = f2b(ldx(cb, F, (size_t)bidx * 64 + d4 + 1));
        h.z = f2b(ldx(cb, F, (size_t)bidx * 64 + d4 + 2));
        h.w = f2b(ldx(cb, F, (size_t)bidx * 64 + d4 + 3));
        *(ushort4*)&out[d4] = h;
    }
}

// ---------------------------------------------------------------- launch
extern "C" void kernel_launch(void* const* d_in, const int* in_sizes, int n_in,
                              void* d_out, int out_size, void* d_ws,
                              size_t ws_size, hipStream_t stream) {
    const void* x = d_in[0];
    const int* y = (const int*)d_in[1];
    const void* enc_w1 = d_in[2];  const void* enc_b1 = d_in[3];
    const void* enc_g1 = d_in[4];  const void* enc_bt1 = d_in[5];
    const void* enc_w2 = d_in[6];  const void* enc_b2 = d_in[7];
    const void* enc_g2 = d_in[8];  const void* enc_bt2 = d_in[9];
    const void* enc_w3 = d_in[10]; const void* enc_b3 = d_in[11];
    const void* enc_g3 = d_in[12]; const void* enc_bt3 = d_in[13];
    const void* mlp_w = d_in[14];  const void* mlp_b = d_in[15];
    const void* codebook = d_in[16];
    const void* spk_emb = d_in[17];
    const void* dec_w1 = d_in[18]; const void* dec_b1 = d_in[19];
    const void* dec_g1 = d_in[20]; const void* dec_bt1 = d_in[21];
    const void* dec_w2 = d_in[22]; const void* dec_b2 = d_in[23];
    const void* dec_g2 = d_in[24]; const void* dec_bt2 = d_in[25];
    const void* dec_w3 = d_in[26]; const void* dec_b3 = d_in[27];

    // repacked weight sizes (elements)
    const size_t SW1 = (size_t)5 * 512 * 96;
    const size_t SW2 = (size_t)5 * 512 * 512;
    const size_t SW3 = SW2;
    const size_t SWM = (size_t)128 * 512;
    const size_t SD1 = (size_t)5 * 1024 * 192;
    const size_t SD2 = (size_t)5 * 1024 * 640;
    const size_t SD3 = (size_t)5 * 128 * 640;
    const size_t HI_TOT = SW1 + SW2 + SW3 + SWM + SD1 + SD2 + SD3;
    const size_t LO_TOT = SW1 + SW2 + SW3 + SWM;

    const size_t PB = (size_t)T_LEN * (192 * 2 + 1024 * 2 + 2048 + 64 * 4 + 640 * 2 + 640 * 2);
    const size_t FIXED = 256 + 65536 + (HI_TOT + LO_TOT) * 2;

    int nb = BATCH;
    while (nb > 1 && FIXED + (size_t)nb * PB > ws_size) nb >>= 1;

    char* p = (char*)d_ws;
    int* dflag = (int*)p;        p += 256;
    float* spk_n = (float*)p;    p += 65536;
    bf16* w1h = (bf16*)p;        p += SW1 * 2;
    bf16* w2h = (bf16*)p;        p += SW2 * 2;
    bf16* w3h = (bf16*)p;        p += SW3 * 2;
    bf16* wmh = (bf16*)p;        p += SWM * 2;
    bf16* wd1 = (bf16*)p;        p += SD1 * 2;
    bf16* wd2 = (bf16*)p;        p += SD2 * 2;
    bf16* wd3 = (bf16*)p;        p += SD3 * 2;
    bf16* w1l = (bf16*)p;        p += SW1 * 2;
    bf16* w2l = (bf16*)p;        p += SW2 * 2;
    bf16* w3l = (bf16*)p;        p += SW3 * 2;
    bf16* wml = (bf16*)p;        p += SWM * 2;
    bf16* xp = (bf16*)p;         p += (size_t)nb * T_LEN * 192 * 2;  // aliases D1
    bf16* E = (bf16*)p;          p += (size_t)nb * T_LEN * 1024 * 2;
    char* Fb = p;                p += (size_t)nb * T_LEN * 2048;     // f32x512 / bf16x1024
    float* zbuf = (float*)p;     p += (size_t)nb * T_LEN * 64 * 4;
    bf16* D2 = (bf16*)p;         p += (size_t)nb * T_LEN * 640 * 2;
    bf16* D3 = (bf16*)p;
    bf16* D1 = xp;
    float* Ff = (float*)Fb;
    bf16* Fh = (bf16*)Fb;

    dim3 blk(256);

    detect_kernel<<<1, 256, 0, stream>>>((const float*)x, dflag);
    spk_norm_kernel<<<128, 128, 0, stream>>>(dflag, spk_emb, spk_n);

    // repack weights (coalesced tiles)
    repack0_kernel<<<dim3(3, 8), blk, 0, stream>>>(dflag, enc_w1, 512, 80, 5, 512, 96, w1h, w1l);
    repack0_kernel<<<dim3(16, 8), blk, 0, stream>>>(dflag, enc_w2, 512, 512, 5, 512, 512, w2h, w2l);
    repack0_kernel<<<dim3(16, 8), blk, 0, stream>>>(dflag, enc_w3, 512, 512, 5, 512, 512, w3h, w3l);
    repack0_kernel<<<dim3(16, 2), blk, 0, stream>>>(dflag, mlp_w, 64, 512, 1, 128, 512, wmh, wml);
    repack1_kernel<<<dim3(3, 32), blk, 0, stream>>>(dflag, dec_w1, 1024, 192, 5, 1024, 192, wd1);
    repack1_kernel<<<dim3(10, 32), blk, 0, stream>>>(dflag, dec_w2, 1024, 640, 5, 1024, 640, wd2);
    repack1_kernel<<<dim3(10, 4), blk, 0, stream>>>(dflag, dec_w3, 80, 640, 5, 128, 640, wd3);

    for (int b0 = 0; b0 < BATCH; b0 += nb) {
        dim3 gT(T_LEN / 256, nb);
        dim3 gLN(T_LEN / 4, nb);

        xprep_kernel<<<gT, blk, 0, stream>>>(dflag, x, b0, xp);

        // encoder (bf16 hi/lo pair intermediates)
        conv_mfma<5, 2><<<dim3(16, 8, nb), blk, 0, stream>>>(
            dflag, xp, 192, 96, 2, 96, w1h, w1l, 2, 512, enc_b1, Ff, 0, 512, 512, 0);
        // ye written after enc1 consumed xp (D1 aliases xp)
        ye_kernel<<<gT, blk, 0, stream>>>(y, b0, spk_n, D1, D2, D3);
        ln_lrelu<<<gLN, blk, 0, stream>>>(dflag, Ff, E, enc_g1, enc_bt1);
        conv_mfma<5, 2><<<dim3(16, 8, nb), blk, 0, stream>>>(
            dflag, E, 1024, 512, 1, 512, w2h, w2l, 2, 512, enc_b2, Ff, 0, 512, 512, 0);
        ln_lrelu<<<gLN, blk, 0, stream>>>(dflag, Ff, E, enc_g2, enc_bt2);
        conv_mfma<5, 2><<<dim3(16, 8, nb), blk, 0, stream>>>(
            dflag, E, 1024, 512, 1, 512, w3h, w3l, 2, 512, enc_b3, Ff, 0, 512, 512, 0);
        ln_lrelu<<<gLN, blk, 0, stream>>>(dflag, Ff, E, enc_g3, enc_bt3);

        // 1x1 conv to z
        conv_mfma<1, 2><<<dim3(16, 1, nb), blk, 0, stream>>>(
            dflag, E, 1024, 512, 1, 512, wmh, wml, 2, 128, mlp_b, zbuf, 0, 64, 64, 0);

        // vector quantize -> D1 cols [0,64)
        vq_kernel<<<gT, blk, 0, stream>>>(dflag, zbuf, codebook, D1);

        // decoder (bf16 intermediates)
        conv_mfma<5, 1><<<dim3(16, 16, nb), blk, 0, stream>>>(
            dflag, D1, 192, 0, 0, 192, wd1, nullptr, 0, 1024, dec_b1, Fh, 1, 1024, 1024, 0);
        ln_glu<<<gLN, blk, 0, stream>>>(dflag, Fh, D2, 640, dec_g1, dec_bt1);
        conv_mfma<5, 1><<<dim3(16, 16, nb), blk, 0, stream>>>(
            dflag, D2, 640, 0, 0, 640, wd2, nullptr, 0, 1024, dec_b2, Fh, 1, 1024, 1024, 0);
        ln_glu<<<gLN, blk, 0, stream>>>(dflag, Fh, D3, 640, dec_g2, dec_bt2);
        conv_mfma<5, 1><<<dim3(16, 2, nb), blk, 0, stream>>>(
            dflag, D3, 640, 0, 0, 640, wd3, nullptr, 0, 128, dec_b3, d_out, 2, 80, 80, b0);
    }
}